// Round 1
// baseline (95.544 us; speedup 1.0000x reference)
//
#include <hip/hip_runtime.h>
#include <math.h>

// Problem constants (match reference)
#define NSEQ 64
#define TLEN 32768
#define G16_PER_SEQ 2048              // TLEN/16
#define NG16 (NSEQ * G16_PER_SEQ)     // 131072 level-16 groups
#define N0 5
#define DT 0.01f
#define HUBER_INV 200.0f              // 1/0.005

// W*HUBER^2 = 25.  mean denominators: 64*2043*3 and 64*1019*3; level-32 has extra 1/2.
__device__ __constant__ float C16 = 25.0f / (64.0f * 2043.0f * 3.0f);
__device__ __constant__ float C32 = 12.5f / (64.0f * 1019.0f * 3.0f);

__device__ __forceinline__ void mat_mul3(const float* A, const float* B, float* C) {
#pragma unroll
    for (int i = 0; i < 3; ++i) {
#pragma unroll
        for (int j = 0; j < 3; ++j) {
            C[3 * i + j] = A[3 * i + 0] * B[0 + j]
                         + A[3 * i + 1] * B[3 + j]
                         + A[3 * i + 2] * B[6 + j];
        }
    }
}

// Rodrigues: R = (1 - c*sq)I + s*K + c*v v^T, matching reference small-angle branches
__device__ __forceinline__ void so3_exp_dev(float x, float y, float z, float* R) {
    float sq = x * x + y * y + z * z;
    float angle = sqrtf(fmaxf(sq, 1e-16f));
    bool small = sq < 1e-12f;
    float a = small ? 1.0f : angle;
    float sn, cs;
    __sincosf(a, &sn, &cs);
    float s = small ? (1.0f - sq * (1.0f / 6.0f)) : (sn / a);
    float c = small ? (0.5f - sq * (1.0f / 24.0f)) : ((1.0f - cs) / (a * a));
    float cxx = c * x * x, cyy = c * y * y, czz = c * z * z;
    float cxy = c * x * y, cxz = c * x * z, cyz = c * y * z;
    float sx = s * x, sy = s * y, sz = s * z;
    R[0] = 1.0f - cyy - czz; R[1] = cxy - sz;          R[2] = cxz + sy;
    R[3] = cxy + sz;         R[4] = 1.0f - cxx - czz;  R[5] = cyz - sx;
    R[6] = cxz - sy;         R[7] = cyz + sx;          R[8] = 1.0f - cxx - cyy;
}

// huber-sum over 3 components of log(Om^T * Xr) / HUBER
__device__ __forceinline__ float huber3_bmtm_log(const float* Om, const float* Xr) {
    float M[9];
#pragma unroll
    for (int j = 0; j < 3; ++j) {
#pragma unroll
        for (int k = 0; k < 3; ++k) {
            M[3 * j + k] = Om[0 + j] * Xr[0 + k]
                         + Om[3 + j] * Xr[3 + k]
                         + Om[6 + j] * Xr[6 + k];
        }
    }
    float tr = M[0] + M[4] + M[8];
    float cosv = 0.5f * (tr - 1.0f);
    cosv = fminf(fmaxf(cosv, -1.0f + 1e-7f), 1.0f - 1e-7f);
    float angle = acosf(cosv);
    float sn = sqrtf(fmaxf(1.0f - cosv * cosv, 0.0f));   // sin(acos(x)) in (0,pi)
    float sfac = angle / (2.0f * sn);
    float v[3];
    v[0] = sfac * (M[7] - M[5]);
    v[1] = sfac * (M[2] - M[6]);
    v[2] = sfac * (M[3] - M[1]);
    float acc = 0.0f;
#pragma unroll
    for (int t = 0; t < 3; ++t) {
        float zz = v[t] * HUBER_INV;
        float az = fabsf(zz);
        acc += (az < 1.0f) ? 0.5f * zz * zz : az - 0.5f;
    }
    return acc;
}

__global__ void zero_out_kernel(float* out, int n) {
    int i = blockIdx.x * blockDim.x + threadIdx.x;
    if (i < n) out[i] = 0.0f;
}

__global__ __launch_bounds__(256) void gyro_loss_kernel(const float* __restrict__ xs,
                                                        const float* __restrict__ hat_xs,
                                                        float* __restrict__ out) {
    const int g = blockIdx.x * blockDim.x + threadIdx.x;   // level-16 group id, 0..NG16-1

    // ---- load the 48 floats (16 steps x 3) of hat_xs for this group, float4-aligned ----
    const float4* hp = reinterpret_cast<const float4*>(hat_xs) + (size_t)g * 12;
    float hbuf[48];
#pragma unroll
    for (int q = 0; q < 12; ++q) {
        float4 vv = hp[q];
        hbuf[4 * q + 0] = vv.x; hbuf[4 * q + 1] = vv.y;
        hbuf[4 * q + 2] = vv.z; hbuf[4 * q + 3] = vv.w;
    }

    // ---- ordered product of 16 per-step rotations ----
    float Om[9];
    so3_exp_dev(DT * hbuf[0], DT * hbuf[1], DT * hbuf[2], Om);
#pragma unroll
    for (int i = 1; i < 16; ++i) {
        float Ri[9], tmp[9];
        so3_exp_dev(DT * hbuf[3 * i + 0], DT * hbuf[3 * i + 1], DT * hbuf[3 * i + 2], Ri);
        mat_mul3(Om, Ri, tmp);
#pragma unroll
        for (int t = 0; t < 9; ++t) Om[t] = tmp[t];
    }

    // ---- xs_r for this group: xs element 16*g -> float offset 48*g (16B aligned) ----
    float4 xv = *(reinterpret_cast<const float4*>(xs) + (size_t)g * 12);
    float Xr[9];
    so3_exp_dev(xv.x, xv.y, xv.z, Xr);

    float partial = 0.0f;
    const int j = g & (G16_PER_SEQ - 1);
    if (j >= N0) partial += C16 * huber3_bmtm_log(Om, Xr);

    // ---- level 32: pair adjacent lanes ----
    float OmN[9], XrN[9];
#pragma unroll
    for (int t = 0; t < 9; ++t) {
        OmN[t] = __shfl_down(Om[t], 1);
        XrN[t] = __shfl_down(Xr[t], 1);
    }
    if ((g & 1) == 0) {
        float Om32[9], Xr32[9];
        mat_mul3(Om, OmN, Om32);
        mat_mul3(Xr, XrN, Xr32);
        const int j2 = (g >> 1) & ((G16_PER_SEQ / 2) - 1);
        if (j2 >= N0) partial += C32 * huber3_bmtm_log(Om32, Xr32);
    }

    // ---- reduction: wave shuffle -> LDS -> one atomic per block ----
#pragma unroll
    for (int off = 32; off > 0; off >>= 1) partial += __shfl_down(partial, off);

    __shared__ float wsum[4];
    const int lane = threadIdx.x & 63;
    const int wid = threadIdx.x >> 6;
    if (lane == 0) wsum[wid] = partial;
    __syncthreads();
    if (threadIdx.x == 0) {
        atomicAdd(out, wsum[0] + wsum[1] + wsum[2] + wsum[3]);
    }
}

extern "C" void kernel_launch(void* const* d_in, const int* in_sizes, int n_in,
                              void* d_out, int out_size, void* d_ws, size_t ws_size,
                              hipStream_t stream) {
    const float* xs     = (const float*)d_in[0];
    // d_in[1] = dp, unused by the forward pass
    const float* hat_xs = (const float*)d_in[2];
    float* out = (float*)d_out;

    zero_out_kernel<<<1, 64, 0, stream>>>(out, out_size);
    gyro_loss_kernel<<<NG16 / 256, 256, 0, stream>>>(xs, hat_xs, out);
}